// Round 2
// baseline (131.618 us; speedup 1.0000x reference)
//
#include <hip/hip_runtime.h>

// QFCModel: avg-pool 6x6 -> 16 angles -> 4-qubit product-state circuit -> <Z> -> log_softmax
// R2: wave-autonomous pipeline. One block = one wave = 64 images. No __syncthreads.
// 16 chunks x 4 images; 2-deep register prefetch (rA/rB) so HBM latency (~900cy)
// is covered by two pool phases. LDS per block: 4-image linear stage (9216 B) +
// XOR-swizzled xp[16][64] (4096 B) = 13.3 KB.

__device__ __forceinline__ void cmul(float ar, float ai, float br, float bi,
                                     float& cr, float& ci) {
  cr = ar * br - ai * bi;
  ci = ar * bi + ai * br;
}

struct C2 { float r0, i0, r1, i1; };

__device__ __forceinline__ void g_rx(C2& v, float h) {
  float s, c; __sincosf(h, &s, &c);
  C2 n;
  n.r0 = c * v.r0 + s * v.i1;
  n.i0 = c * v.i0 - s * v.r1;
  n.r1 = c * v.r1 + s * v.i0;
  n.i1 = c * v.i1 - s * v.r0;
  v = n;
}
__device__ __forceinline__ void g_ry(C2& v, float h) {
  float s, c; __sincosf(h, &s, &c);
  C2 n;
  n.r0 = c * v.r0 - s * v.r1;
  n.i0 = c * v.i0 - s * v.i1;
  n.r1 = s * v.r0 + c * v.r1;
  n.i1 = s * v.i0 + c * v.i1;
  v = n;
}
__device__ __forceinline__ void g_rz(C2& v, float h) {
  float s, c; __sincosf(h, &s, &c);
  C2 n;
  n.r0 = c * v.r0 + s * v.i0;
  n.i0 = c * v.i0 - s * v.r0;
  n.r1 = c * v.r1 - s * v.i1;
  n.i1 = c * v.i1 + s * v.r1;
  v = n;
}

#define NC 16   // chunks per wave; chunk = 4 images = 576 float4

__global__ __launch_bounds__(64, 2)
void qfc_kernel(const float* __restrict__ x,
                const float* __restrict__ thrx,
                const float* __restrict__ thry,
                const float* __restrict__ thrz,
                const float* __restrict__ thcrx,
                float* __restrict__ out) {
  __shared__ float stage[2304];   // 4 images x 576 floats, linear
  __shared__ float xp[1024];      // [pool p][col], col = img64 ^ ((p<<2)&63)

  const int l = threadIdx.x;                       // 0..63
  const long long img0 = (long long)blockIdx.x * 64;
  const float4* __restrict__ base4 =
      reinterpret_cast<const float4*>(x) + img0 * 144;

  float4 rA[9], rB[9];

  auto issue = [&](float4* r, int c) {
    const int b = c * 576 + l;
#pragma unroll
    for (int k = 0; k < 9; ++k) r[k] = base4[b + k * 64];
  };
  auto put = [&](const float4* r) {
#pragma unroll
    for (int k = 0; k < 9; ++k)
      *reinterpret_cast<float4*>(&stage[(k * 64 + l) * 4]) = r[k];
  };
  auto pool = [&](int c) {
    const int img = l >> 4;          // 0..3 within chunk
    const int p = l & 15;            // r0*4 + c0
    const int r0 = p >> 2, c0 = p & 3;
    const float* b = &stage[img * 576 + r0 * 144 + c0 * 6];
    float sum = 0.f;
#pragma unroll
    for (int r = 0; r < 6; ++r) {
      float2 a0 = *reinterpret_cast<const float2*>(b + r * 24);
      float2 a1 = *reinterpret_cast<const float2*>(b + r * 24 + 2);
      float2 a2 = *reinterpret_cast<const float2*>(b + r * 24 + 4);
      sum += a0.x + a0.y + a1.x + a1.y + a2.x + a2.y;
    }
    const int col = (c * 4 + img) ^ ((p << 2) & 63);  // bank-spread (2-way free)
    xp[p * 64 + col] = sum * (1.0f / 36.0f);
  };

  // ---- barrier-free pipeline, 2-deep prefetch ----
  issue(rA, 0);
  issue(rB, 1);
  for (int cc = 0; cc < NC; cc += 2) {
    put(rA);
    if (cc + 2 < NC) issue(rA, cc + 2);
    pool(cc);
    put(rB);
    if (cc + 3 < NC) issue(rB, cc + 3);
    pool(cc + 1);
  }

  // ---- circuit: one lane = one image ----
  float a[16];
#pragma unroll
  for (int p = 0; p < 16; ++p) a[p] = xp[p * 64 + (l ^ ((p << 2) & 63))];

  const float arx = thrx[0] * 0.5f;
  const float ary = thry[0] * 0.5f;
  const float arz = thrz[0] * 0.5f;
  const float acr = thcrx[0] * 0.5f;

  // product state: encoder (RX,RY,RZ,RX) + trainable RX0/RY1/RZ3 fold per-wire
  C2 v[4];
#pragma unroll
  for (int w = 0; w < 4; ++w) {
    v[w].r0 = 1.f; v[w].i0 = 0.f; v[w].r1 = 0.f; v[w].i1 = 0.f;
    g_rx(v[w], a[w] * 0.5f);
    g_ry(v[w], a[4 + w] * 0.5f);
    g_rz(v[w], a[8 + w] * 0.5f);
    g_rx(v[w], a[12 + w] * 0.5f);
  }
  g_rx(v[0], arx);
  g_ry(v[1], ary);
  g_rz(v[3], arz);

  float t01r[4], t01i[4], t23r[4], t23i[4];
  cmul(v[0].r0, v[0].i0, v[1].r0, v[1].i0, t01r[0], t01i[0]);
  cmul(v[0].r0, v[0].i0, v[1].r1, v[1].i1, t01r[1], t01i[1]);
  cmul(v[0].r1, v[0].i1, v[1].r0, v[1].i0, t01r[2], t01i[2]);
  cmul(v[0].r1, v[0].i1, v[1].r1, v[1].i1, t01r[3], t01i[3]);
  cmul(v[2].r0, v[2].i0, v[3].r0, v[3].i0, t23r[0], t23i[0]);
  cmul(v[2].r0, v[2].i0, v[3].r1, v[3].i1, t23r[1], t23i[1]);
  cmul(v[2].r1, v[2].i1, v[3].r0, v[3].i0, t23r[2], t23i[2]);
  cmul(v[2].r1, v[2].i1, v[3].r1, v[3].i1, t23r[3], t23i[3]);

  float re[16], im[16];   // idx = w0*8 + w1*4 + w2*2 + w3
#pragma unroll
  for (int hi = 0; hi < 4; ++hi)
#pragma unroll
    for (int lo = 0; lo < 4; ++lo)
      cmul(t01r[hi], t01i[hi], t23r[lo], t23i[lo], re[hi * 4 + lo], im[hi * 4 + lo]);

  // CRX(theta) control w0, target w2: RX on pairs (i,i+2), i in {8,9,12,13}
  {
    float s, cc2; __sincosf(acr, &s, &cc2);
#pragma unroll
    for (int k = 0; k < 4; ++k) {
      const int pi4[4] = {8, 9, 12, 13};
      int i = pi4[k], j = i + 2;
      float nir = cc2 * re[i] + s * im[j];
      float nii = cc2 * im[i] - s * re[j];
      float njr = cc2 * re[j] + s * im[i];
      float nji = cc2 * im[j] - s * re[i];
      re[i] = nir; im[i] = nii; re[j] = njr; im[j] = nji;
    }
  }
  // H on wire 3
#pragma unroll
  for (int i = 0; i < 16; i += 2) {
    const float inv = 0.70710678118654752f;
    float ar = re[i], ai = im[i], br = re[i + 1], bi = im[i + 1];
    re[i] = (ar + br) * inv;     im[i] = (ai + bi) * inv;
    re[i + 1] = (ar - br) * inv; im[i + 1] = (ai - bi) * inv;
  }
  // SX on wire 2
#pragma unroll
  for (int i = 0; i < 16; ++i) {
    if ((i & 2) == 0) {
      int j = i + 2;
      float ar = re[i], ai = im[i], br = re[j], bi = im[j];
      re[i] = 0.5f * (ar - ai + br + bi);
      im[i] = 0.5f * (ar + ai - br + bi);
      re[j] = 0.5f * (ar + ai + br - bi);
      im[j] = 0.5f * (ai - ar + br + bi);
    }
  }
  // CNOT control w3, target w0: swap (i, i+8) for odd i < 8
#pragma unroll
  for (int i = 1; i < 8; i += 2) {
    float tr = re[i], ti = im[i];
    re[i] = re[i + 8]; im[i] = im[i + 8];
    re[i + 8] = tr;    im[i + 8] = ti;
  }
  // U12 on wires (1,2)
#pragma unroll
  for (int k = 0; k < 4; ++k) {
    const int ii4[4] = {4, 5, 12, 13};
    int i = ii4[k], j = i + 2;
    float tr = re[i], ti = im[i];
    re[i] = -im[j]; im[i] = re[j];
    re[j] = ti;     im[j] = -tr;
  }

  // <Z_w> -> logits -> log_softmax
  float z0 = 0.f, z1 = 0.f, z2 = 0.f, z3 = 0.f;
#pragma unroll
  for (int i = 0; i < 16; ++i) {
    float p = re[i] * re[i] + im[i] * im[i];
    z0 += (i & 8) ? -p : p;
    z1 += (i & 4) ? -p : p;
    z2 += (i & 2) ? -p : p;
    z3 += (i & 1) ? -p : p;
  }
  float l0 = z0 + z1, l1 = z2 + z3;
  float m = fmaxf(l0, l1);
  float e0 = __expf(l0 - m), e1 = __expf(l1 - m);
  float lse = __logf(e0 + e1);
  float2 o;
  o.x = l0 - m - lse;
  o.y = l1 - m - lse;
  reinterpret_cast<float2*>(out)[img0 + l] = o;
}

extern "C" void kernel_launch(void* const* d_in, const int* in_sizes, int n_in,
                              void* d_out, int out_size, void* d_ws, size_t ws_size,
                              hipStream_t stream) {
  const float* x = (const float*)d_in[0];
  const float* thrx = (const float*)d_in[1];
  const float* thry = (const float*)d_in[2];
  const float* thrz = (const float*)d_in[3];
  const float* thcrx = (const float*)d_in[4];
  float* out = (float*)d_out;
  // 131072 images / 64 per wave-block = 2048 blocks
  qfc_kernel<<<2048, 64, 0, stream>>>(x, thrx, thry, thrz, thcrx, out);
}

// Round 3
// 57.039 us; speedup vs baseline: 2.3075x; 2.3075x over previous
//
#include <hip/hip_runtime.h>

// QFCModel: avg-pool 6x6 -> 16 angles -> 4-qubit product-state circuit -> <Z> -> log_softmax
// R3: R1's block-cooperative double-buffered pipeline, upgraded:
//  - 1024 blocks x 128 images (LDS 45.3KB -> 3 blocks/CU = 12 waves/CU)
//  - global_load_lds width-16 staging (no VGPR round trip), raw s_barrier +
//    hand-counted vmcnt(N) (2 chunks in flight, never drained mid-loop)
//  - LDS kept linear for global_load_lds; bank spread via XOR-swizzled GLOBAL
//    source (involution: f4idx ^= img&7 within each 144-f4 image), pool reads
//    apply the same XOR (both-sides-or-neither).
//  - pool split across lane pairs (3 rows each + __shfl_xor combine) so all
//    4 waves participate.

#define GL2LDS(gp, lp)                                             \
  __builtin_amdgcn_global_load_lds(                                \
      (const __attribute__((address_space(1))) void*)(gp),         \
      (__attribute__((address_space(3))) void*)(lp), 16, 0, 0)
#define BAR() __builtin_amdgcn_s_barrier()
#define WAITVM(N) asm volatile("s_waitcnt vmcnt(" #N ")" ::: "memory")
#define WAITLGKM() asm volatile("s_waitcnt lgkmcnt(0)" ::: "memory")

#define NCHUNK 16        // 128 images / 8 per chunk
#define CH_F4 1152       // 8 images * 144 float4
#define STG_F 4608       // floats per stage buffer (1152 f4)
#define XPS 132          // xp row stride (floats)

__device__ __forceinline__ void cmul(float ar, float ai, float br, float bi,
                                     float& cr, float& ci) {
  cr = ar * br - ai * bi;
  ci = ar * bi + ai * br;
}

struct C2 { float r0, i0, r1, i1; };

__device__ __forceinline__ void g_rx(C2& v, float h) {
  float s, c; __sincosf(h, &s, &c);
  C2 n;
  n.r0 = c * v.r0 + s * v.i1;
  n.i0 = c * v.i0 - s * v.r1;
  n.r1 = c * v.r1 + s * v.i0;
  n.i1 = c * v.i1 - s * v.r0;
  v = n;
}
__device__ __forceinline__ void g_ry(C2& v, float h) {
  float s, c; __sincosf(h, &s, &c);
  C2 n;
  n.r0 = c * v.r0 - s * v.r1;
  n.i0 = c * v.i0 - s * v.i1;
  n.r1 = s * v.r0 + c * v.r1;
  n.i1 = s * v.i0 + c * v.i1;
  v = n;
}
__device__ __forceinline__ void g_rz(C2& v, float h) {
  float s, c; __sincosf(h, &s, &c);
  C2 n;
  n.r0 = c * v.r0 + s * v.i0;
  n.i0 = c * v.i0 - s * v.r0;
  n.r1 = c * v.r1 - s * v.i1;
  n.i1 = c * v.i1 + s * v.r1;
  v = n;
}

__global__ __launch_bounds__(256, 3)
void qfc_kernel(const float* __restrict__ x,
                const float* __restrict__ thrx,
                const float* __restrict__ thry,
                const float* __restrict__ thrz,
                const float* __restrict__ thcrx,
                float* __restrict__ out) {
  __shared__ float stage[2 * STG_F];   // linear (global_load_lds dest)
  __shared__ float xp[16 * XPS];       // [pool p][image col], stride 132

  const int t = threadIdx.x;
  const int w = t >> 6;                            // wave id 0..3
  const long long img0 = (long long)blockIdx.x * 128;
  const float4* __restrict__ base4 =
      reinterpret_cast<const float4*>(x) + img0 * 144;

  // ---- staging: LDS slot L <- global f4 (L ^ (img&7)); involution within image
  auto issue = [&](int c, int buf) {
    const float4* gsrc = base4 + c * CH_F4;
    float* lbase = stage + buf * STG_F;
#pragma unroll
    for (int k = 0; k < 4; ++k) {
      const int L = k * 256 + t;
      const int img = L / 144;
      const int g = L ^ (img & 7);
      GL2LDS(gsrc + g, lbase + (k * 256 + w * 64) * 4);
    }
    if (t < 128) {                      // waves 0,1 issue a 5th load
      const int L = 1024 + t;
      const int img = L / 144;
      const int g = L ^ (img & 7);
      GL2LDS(gsrc + g, lbase + (1024 + w * 64) * 4);
    }
  };

  // ---- pool: 2 lanes per output (3 rows each), shfl-combine; all 4 waves busy
  auto pool = [&](int c, int buf) {
    const float* lb = stage + buf * STG_F;
    const int img = t >> 5;            // 0..7
    const int p = (t & 31) >> 1;       // 0..15 = r0*4 + c0
    const int half = t & 1;
    const int r0 = p >> 2, c0 = p & 3;
    float sum = 0.f;
#pragma unroll
    for (int r = 0; r < 3; ++r) {
      const int row = r0 * 6 + half * 3 + r;
#pragma unroll
      for (int off = 0; off < 6; off += 2) {
        const int f = row * 24 + c0 * 6 + off;           // float idx in image
        const int slot = (img * 144 + (f >> 2)) ^ img;   // swizzled f4 slot
        const float2 v = *reinterpret_cast<const float2*>(lb + slot * 4 + (f & 3));
        sum += v.x + v.y;
      }
    }
    const float tot = sum + __shfl_xor(sum, 1, 64);
    if (half == 0) xp[p * XPS + c * 8 + img] = tot * (1.0f / 36.0f);
  };

  // ---- pipeline: 2 chunks in flight, counted vmcnt, raw barriers ----
  issue(0, 0);
  issue(1, 1);
  for (int c = 0; c < NCHUNK; ++c) {
    if (c < NCHUNK - 1) {
      if (w < 2) WAITVM(5); else WAITVM(4);   // drain chunk c, keep c+1 in flight
    } else {
      WAITVM(0);
    }
    BAR();                 // all waves' chunk-c LDS writes landed
    pool(c, c & 1);
    BAR();                 // all pool reads of buf[c&1] done (WAR guard)
    if (c + 2 < NCHUNK) issue(c + 2, c & 1);
  }
  WAITLGKM();              // xp ds_writes visible
  BAR();

  // ---- circuit: one thread = one image (t < 128) ----
  if (t < 128) {
    float a[16];
#pragma unroll
    for (int p = 0; p < 16; ++p) a[p] = xp[p * XPS + t];

    const float arx = thrx[0] * 0.5f;
    const float ary = thry[0] * 0.5f;
    const float arz = thrz[0] * 0.5f;
    const float acr = thcrx[0] * 0.5f;

    C2 v[4];
#pragma unroll
    for (int wi = 0; wi < 4; ++wi) {
      v[wi].r0 = 1.f; v[wi].i0 = 0.f; v[wi].r1 = 0.f; v[wi].i1 = 0.f;
      g_rx(v[wi], a[wi] * 0.5f);
      g_ry(v[wi], a[4 + wi] * 0.5f);
      g_rz(v[wi], a[8 + wi] * 0.5f);
      g_rx(v[wi], a[12 + wi] * 0.5f);
    }
    g_rx(v[0], arx);
    g_ry(v[1], ary);
    g_rz(v[3], arz);

    float t01r[4], t01i[4], t23r[4], t23i[4];
    cmul(v[0].r0, v[0].i0, v[1].r0, v[1].i0, t01r[0], t01i[0]);
    cmul(v[0].r0, v[0].i0, v[1].r1, v[1].i1, t01r[1], t01i[1]);
    cmul(v[0].r1, v[0].i1, v[1].r0, v[1].i0, t01r[2], t01i[2]);
    cmul(v[0].r1, v[0].i1, v[1].r1, v[1].i1, t01r[3], t01i[3]);
    cmul(v[2].r0, v[2].i0, v[3].r0, v[3].i0, t23r[0], t23i[0]);
    cmul(v[2].r0, v[2].i0, v[3].r1, v[3].i1, t23r[1], t23i[1]);
    cmul(v[2].r1, v[2].i1, v[3].r0, v[3].i0, t23r[2], t23i[2]);
    cmul(v[2].r1, v[2].i1, v[3].r1, v[3].i1, t23r[3], t23i[3]);

    float re[16], im[16];   // idx = w0*8 + w1*4 + w2*2 + w3
#pragma unroll
    for (int hi = 0; hi < 4; ++hi)
#pragma unroll
      for (int lo = 0; lo < 4; ++lo)
        cmul(t01r[hi], t01i[hi], t23r[lo], t23i[lo], re[hi * 4 + lo], im[hi * 4 + lo]);

    // CRX ctrl w0, tgt w2: RX on (i,i+2), i in {8,9,12,13}
    {
      float s, cc2; __sincosf(acr, &s, &cc2);
#pragma unroll
      for (int k = 0; k < 4; ++k) {
        const int pi4[4] = {8, 9, 12, 13};
        int i = pi4[k], j = i + 2;
        float nir = cc2 * re[i] + s * im[j];
        float nii = cc2 * im[i] - s * re[j];
        float njr = cc2 * re[j] + s * im[i];
        float nji = cc2 * im[j] - s * re[i];
        re[i] = nir; im[i] = nii; re[j] = njr; im[j] = nji;
      }
    }
    // H on wire 3
#pragma unroll
    for (int i = 0; i < 16; i += 2) {
      const float inv = 0.70710678118654752f;
      float ar = re[i], ai = im[i], br = re[i + 1], bi = im[i + 1];
      re[i] = (ar + br) * inv;     im[i] = (ai + bi) * inv;
      re[i + 1] = (ar - br) * inv; im[i + 1] = (ai - bi) * inv;
    }
    // SX on wire 2
#pragma unroll
    for (int i = 0; i < 16; ++i) {
      if ((i & 2) == 0) {
        int j = i + 2;
        float ar = re[i], ai = im[i], br = re[j], bi = im[j];
        re[i] = 0.5f * (ar - ai + br + bi);
        im[i] = 0.5f * (ar + ai - br + bi);
        re[j] = 0.5f * (ar + ai + br - bi);
        im[j] = 0.5f * (ai - ar + br + bi);
      }
    }
    // CNOT ctrl w3, tgt w0: swap (i, i+8) for odd i < 8
#pragma unroll
    for (int i = 1; i < 8; i += 2) {
      float tr = re[i], ti = im[i];
      re[i] = re[i + 8]; im[i] = im[i + 8];
      re[i + 8] = tr;    im[i + 8] = ti;
    }
    // U12 on wires (1,2)
#pragma unroll
    for (int k = 0; k < 4; ++k) {
      const int ii4[4] = {4, 5, 12, 13};
      int i = ii4[k], j = i + 2;
      float tr = re[i], ti = im[i];
      re[i] = -im[j]; im[i] = re[j];
      re[j] = ti;     im[j] = -tr;
    }

    float z0 = 0.f, z1 = 0.f, z2 = 0.f, z3 = 0.f;
#pragma unroll
    for (int i = 0; i < 16; ++i) {
      float p = re[i] * re[i] + im[i] * im[i];
      z0 += (i & 8) ? -p : p;
      z1 += (i & 4) ? -p : p;
      z2 += (i & 2) ? -p : p;
      z3 += (i & 1) ? -p : p;
    }
    float l0 = z0 + z1, l1 = z2 + z3;
    float m = fmaxf(l0, l1);
    float e0 = __expf(l0 - m), e1 = __expf(l1 - m);
    float lse = __logf(e0 + e1);
    float2 o;
    o.x = l0 - m - lse;
    o.y = l1 - m - lse;
    reinterpret_cast<float2*>(out)[img0 + t] = o;
  }
}

extern "C" void kernel_launch(void* const* d_in, const int* in_sizes, int n_in,
                              void* d_out, int out_size, void* d_ws, size_t ws_size,
                              hipStream_t stream) {
  const float* x = (const float*)d_in[0];
  const float* thrx = (const float*)d_in[1];
  const float* thry = (const float*)d_in[2];
  const float* thrz = (const float*)d_in[3];
  const float* thcrx = (const float*)d_in[4];
  float* out = (float*)d_out;
  // 131072 images / 128 per block = 1024 blocks
  qfc_kernel<<<1024, 256, 0, stream>>>(x, thrx, thry, thrz, thcrx, out);
}